// Round 8
// baseline (160.084 us; speedup 1.0000x reference)
//
#include <hip/hip_runtime.h>

#define C_CH 128
#define I_CH 16
#define NVOX 9216   // 16*24*24
#define BATCH 2
#define LOG2E 1.44269504088896340736f

typedef unsigned short ushort_t;
typedef unsigned int uint_t;
typedef short bf16x8 __attribute__((ext_vector_type(8)));
typedef float f32x4 __attribute__((ext_vector_type(4)));

static __device__ inline ushort_t f2bf_rne(float x) {
    uint_t u = __builtin_bit_cast(uint_t, x);
    u = (u + 0x7FFFu + ((u >> 16) & 1u)) >> 16;
    return (ushort_t)u;
}

static __device__ inline float fast_exp2(float x) {
#if __has_builtin(__builtin_amdgcn_exp2f)
    return __builtin_amdgcn_exp2f(x);
#else
    return exp2f(x);
#endif
}

// ---------------------------------------------------------------------------
// Kernel 1: QKV projection -> bf16 (q pre-scaled by log2e). R7 version
// (TLP-first): 1152 blocks x 256 threads; thread = (voxel n in 16, i in 16).
// ---------------------------------------------------------------------------
__global__ __launch_bounds__(256) void qkv_kernel(
    const float* __restrict__ x,
    const float* __restrict__ Wq, const float* __restrict__ bq,
    const float* __restrict__ Wk, const float* __restrict__ bk,
    const float* __restrict__ Wv, const float* __restrict__ bv,
    ushort_t* __restrict__ qb, ushort_t* __restrict__ kb,
    ushort_t* __restrict__ vT)
{
    __shared__ float ws[3][I_CH][132];   // padded stride 132 -> conflict-free
    __shared__ float xs[C_CH][I_CH];     // 8 KB

    const int t    = threadIdx.x;
    const int vox0 = blockIdx.x * 16;
    const int b    = vox0 / NVOX;
    const int n0   = vox0 - b * NVOX;

    {
        const int i  = t >> 4;           // 0..15
        const int c8 = (t & 15) * 8;     // 0..120
        const float4* wq4 = (const float4*)(Wq + i * C_CH + c8);
        const float4* wk4 = (const float4*)(Wk + i * C_CH + c8);
        const float4* wv4 = (const float4*)(Wv + i * C_CH + c8);
        *(float4*)&ws[0][i][c8]     = wq4[0];
        *(float4*)&ws[0][i][c8 + 4] = wq4[1];
        *(float4*)&ws[1][i][c8]     = wk4[0];
        *(float4*)&ws[1][i][c8 + 4] = wk4[1];
        *(float4*)&ws[2][i][c8]     = wv4[0];
        *(float4*)&ws[2][i][c8 + 4] = wv4[1];
    }

    {
        const float* xb = x + (size_t)b * C_CH * NVOX + n0;
        const int c   = t >> 2;          // 0..63
        const int col = (t & 3) * 4;
        *(float4*)&xs[c][col]      = *(const float4*)(xb + (size_t)c * NVOX + col);
        *(float4*)&xs[c + 64][col] = *(const float4*)(xb + (size_t)(c + 64) * NVOX + col);
    }
    __syncthreads();

    const int n = t & 15;
    const int i = t >> 4;

    float aq = 0.f, ak = 0.f, av = 0.f;
    #pragma unroll 4
    for (int c = 0; c < C_CH; c += 4) {
        float x0 = xs[c + 0][n];
        float x1 = xs[c + 1][n];
        float x2 = xs[c + 2][n];
        float x3 = xs[c + 3][n];
        float4 wq = *(const float4*)&ws[0][i][c];
        float4 wk = *(const float4*)&ws[1][i][c];
        float4 wv = *(const float4*)&ws[2][i][c];
        aq = fmaf(wq.x, x0, fmaf(wq.y, x1, fmaf(wq.z, x2, fmaf(wq.w, x3, aq))));
        ak = fmaf(wk.x, x0, fmaf(wk.y, x1, fmaf(wk.z, x2, fmaf(wk.w, x3, ak))));
        av = fmaf(wv.x, x0, fmaf(wv.y, x1, fmaf(wv.z, x2, fmaf(wv.w, x3, av))));
    }

    const size_t vox = (size_t)vox0 + n;
    qb[vox * I_CH + i] = f2bf_rne((aq + bq[i]) * LOG2E);
    kb[vox * I_CH + i] = f2bf_rne(ak + bk[i]);
    vT[((size_t)b * I_CH + i) * NVOX + n0 + n] = f2bf_rne(av + bv[i]);
}

// ---------------------------------------------------------------------------
// Kernel 2: fused MFMA flash attention + combine + output projection + resid.
// ROUND 8: 1152 blocks x 256 threads (4 waves), 16 queries/block.
// Rationale: 576-block grids quantize to 2.25 blocks/CU -> ~56% utilization
// (the measured invariant across R5-R7). 1152 small blocks (LDS ~12.5 KB,
// ~8/CU capacity) are all co-resident at 4-5/CU -> ~90% util.
// Wave w covers keys [w*2304, (w+1)*2304) in 36 dual-stream iterations of
// 64 keys. Per 32-key stream: 2 score MFMA (16x16x32, K=16 padded), 8 exp2,
// 4 packs, 1 PV MFMA, 1 l-MFMA (A=ones). Epilogue: 2-slot LDS reduce, /l,
// Wo projection, residual. LDS <=2-way padded; no dynamic reg indexing.
// ---------------------------------------------------------------------------
__global__ __launch_bounds__(256) void attn_kernel(
    const ushort_t* __restrict__ qb, const ushort_t* __restrict__ kb,
    const ushort_t* __restrict__ vT,
    const float* __restrict__ Wo, const float* __restrict__ bo,
    const float* __restrict__ gamma, const float* __restrict__ x,
    float* __restrict__ out)
{
    __shared__ float po[2][16][18];     // partial O; stride 18 -> <=2-way
    __shared__ float lsh[4][17];        // per-wave l (16 q)
    __shared__ float aot[16][20];       // ao[i][q], stride 20 (16B rows)
    __shared__ float wo_s[C_CH][17];    // Wo, stride 17 -> conflict-free

    const int tid  = threadIdx.x;
    const int w    = tid >> 6;          // 0..3
    const int lane = tid & 63;
    const int l16  = lane & 15;
    const int quad = lane >> 4;

    // stage Wo: 2048 floats; thread -> (c = tid>>1, i8 = (tid&1)*8)
    {
        const int c  = tid >> 1;
        const int i8 = (tid & 1) * 8;
        float4 w0 = *(const float4*)(Wo + c * I_CH + i8);
        float4 w1 = *(const float4*)(Wo + c * I_CH + i8 + 4);
        *(float4*)&wo_s[c][i8]     = w0;
        *(float4*)&wo_s[c][i8 + 4] = w1;
    }

    const int qvox0 = blockIdx.x * 16;
    const int b     = qvox0 / NVOX;
    const int nloc0 = qvox0 - b * NVOX;

    // Q B-frag (B[k=i][n=q], k = quad*8+j; zero for i>=16)
    bf16x8 qf = (bf16x8)0;
    if (quad < 2)
        qf = __builtin_bit_cast(bf16x8,
             *(const int4*)(qb + (size_t)(qvox0 + l16) * I_CH + quad * 8));

    // key permutation: score-row r -> key (r>>2)*8 + (r&3)  [+4 for tile1]
    const int p0     = ((l16 >> 2) << 3) + (l16 & 3);
    const int mchunk = w * (NVOX / 4);          // 2304 keys per wave
    const ushort_t* kp = kb + ((size_t)b * NVOX + mchunk + p0) * I_CH + (quad & 1) * 8;
    const ushort_t* vp = vT + ((size_t)b * I_CH + l16) * NVOX + mchunk + quad * 8;

    f32x4 O = {0.f,0.f,0.f,0.f};
    f32x4 L = {0.f,0.f,0.f,0.f};
    const f32x4 Z = {0.f,0.f,0.f,0.f};
    int4 onesi; onesi.x = onesi.y = onesi.z = onesi.w = 0x3F803F80;  // bf16 1.0
    const bf16x8 ones = __builtin_bit_cast(bf16x8, onesi);

    int4 ka0 = *(const int4*)(kp);
    int4 ka1 = *(const int4*)(kp + 4 * I_CH);
    int4 va  = *(const int4*)(vp);

    #pragma unroll 2
    for (int it = 0; it < NVOX / 4 / 32; ++it) {
        kp += 32 * I_CH;
        vp += 32;
        int4 ka0n = *(const int4*)(kp);            // prefetch next step
        int4 ka1n = *(const int4*)(kp + 4 * I_CH);
        int4 van  = *(const int4*)(vp);

        f32x4 s0 = __builtin_amdgcn_mfma_f32_16x16x32_bf16(
            __builtin_bit_cast(bf16x8, ka0), qf, Z, 0, 0, 0);
        f32x4 s1 = __builtin_amdgcn_mfma_f32_16x16x32_bf16(
            __builtin_bit_cast(bf16x8, ka1), qf, Z, 0, 0, 0);

        float p00 = fast_exp2(s0.x), p01 = fast_exp2(s0.y);
        float p02 = fast_exp2(s0.z), p03 = fast_exp2(s0.w);
        float p10 = fast_exp2(s1.x), p11 = fast_exp2(s1.y);
        float p12 = fast_exp2(s1.z), p13 = fast_exp2(s1.w);

        uint_t d0 = __builtin_amdgcn_perm(__builtin_bit_cast(uint_t, p01),
                                          __builtin_bit_cast(uint_t, p00), 0x07060302u);
        uint_t d1 = __builtin_amdgcn_perm(__builtin_bit_cast(uint_t, p03),
                                          __builtin_bit_cast(uint_t, p02), 0x07060302u);
        uint_t d2 = __builtin_amdgcn_perm(__builtin_bit_cast(uint_t, p11),
                                          __builtin_bit_cast(uint_t, p10), 0x07060302u);
        uint_t d3 = __builtin_amdgcn_perm(__builtin_bit_cast(uint_t, p13),
                                          __builtin_bit_cast(uint_t, p12), 0x07060302u);
        int4 pbi = make_int4((int)d0, (int)d1, (int)d2, (int)d3);
        bf16x8 pb = __builtin_bit_cast(bf16x8, pbi);

        O = __builtin_amdgcn_mfma_f32_16x16x32_bf16(
            __builtin_bit_cast(bf16x8, va), pb, O, 0, 0, 0);
        L = __builtin_amdgcn_mfma_f32_16x16x32_bf16(ones, pb, L, 0, 0, 0);

        ka0 = ka0n; ka1 = ka1n; va = van;
    }

    // ---- stage A: waves 0-1 deposit O; every wave deposits l ----
    if (w < 2) {
        #pragma unroll
        for (int r = 0; r < 4; ++r) po[w][quad * 4 + r][l16] = O[r];
    }
    if (quad == 0) lsh[w][l16] = L.x;
    __syncthreads();

    // ---- stage B: waves 2-3 accumulate into slot w-2 ----
    if (w >= 2) {
        #pragma unroll
        for (int r = 0; r < 4; ++r) po[w - 2][quad * 4 + r][l16] += O[r];
    }
    __syncthreads();

    // ---- combine: 256 threads -> aot[i][q] = (sum O)/(sum l) ----
    {
        const int q = tid & 15;
        const int i = tid >> 4;
        float v = po[0][i][q] + po[1][i][q];
        float l = (lsh[0][q] + lsh[1][q]) + (lsh[2][q] + lsh[3][q]);
        aot[i][q] = v / l;
    }
    __syncthreads();

    // ---- projection + residual: thread -> (c = tid>>1, 8 queries) ----
    const float g  = gamma[0];
    const int   c  = tid >> 1;          // 0..127
    const int   q8 = (tid & 1) * 8;     // 0 or 8

    float acc[8];
    {
        const float b0 = bo[c];
        #pragma unroll
        for (int q = 0; q < 8; ++q) acc[q] = b0;
    }
    #pragma unroll
    for (int i = 0; i < 16; ++i) {
        const float wv = wo_s[c][i];
        float4 a0 = *(const float4*)&aot[i][q8];
        float4 a1 = *(const float4*)&aot[i][q8 + 4];
        acc[0] = fmaf(wv, a0.x, acc[0]); acc[1] = fmaf(wv, a0.y, acc[1]);
        acc[2] = fmaf(wv, a0.z, acc[2]); acc[3] = fmaf(wv, a0.w, acc[3]);
        acc[4] = fmaf(wv, a1.x, acc[4]); acc[5] = fmaf(wv, a1.y, acc[5]);
        acc[6] = fmaf(wv, a1.z, acc[6]); acc[7] = fmaf(wv, a1.w, acc[7]);
    }

    const size_t gi = ((size_t)b * C_CH + c) * NVOX + nloc0 + q8;
    float4 x0 = *(const float4*)(x + gi);
    float4 x1 = *(const float4*)(x + gi + 4);
    float4 o0, o1;
    o0.x = fmaf(g, acc[0], x0.x); o0.y = fmaf(g, acc[1], x0.y);
    o0.z = fmaf(g, acc[2], x0.z); o0.w = fmaf(g, acc[3], x0.w);
    o1.x = fmaf(g, acc[4], x1.x); o1.y = fmaf(g, acc[5], x1.y);
    o1.z = fmaf(g, acc[6], x1.z); o1.w = fmaf(g, acc[7], x1.w);
    *(float4*)(out + gi)     = o0;
    *(float4*)(out + gi + 4) = o1;
}

// ---------------------------------------------------------------------------
extern "C" void kernel_launch(void* const* d_in, const int* in_sizes, int n_in,
                              void* d_out, int out_size, void* d_ws, size_t ws_size,
                              hipStream_t stream) {
    const float* x     = (const float*)d_in[0];
    const float* Wq    = (const float*)d_in[1];
    const float* bq    = (const float*)d_in[2];
    const float* Wk    = (const float*)d_in[3];
    const float* bk    = (const float*)d_in[4];
    const float* Wv    = (const float*)d_in[5];
    const float* bv    = (const float*)d_in[6];
    const float* Wo    = (const float*)d_in[7];
    const float* bo    = (const float*)d_in[8];
    const float* gamma = (const float*)d_in[9];
    float* out = (float*)d_out;

    ushort_t* qb = (ushort_t*)d_ws;
    ushort_t* kb = qb + (size_t)BATCH * NVOX * I_CH;
    ushort_t* vT = kb + (size_t)BATCH * NVOX * I_CH;
    // attn prefetch may read ~64B past a wave's K/V range; ws slack covers it.

    hipLaunchKernelGGL(qkv_kernel, dim3(BATCH * NVOX / 16), dim3(256), 0, stream,
                       x, Wq, bq, Wk, bk, Wv, bv, qb, kb, vT);
    hipLaunchKernelGGL(attn_kernel, dim3(BATCH * NVOX / 16), dim3(256), 0, stream,
                       qb, kb, vT, Wo, bo, gamma, x, out);
}

// Round 9
// 127.857 us; speedup vs baseline: 1.2521x; 1.2521x over previous
//
#include <hip/hip_runtime.h>

#define C_CH 128
#define I_CH 16
#define NVOX 9216   // 16*24*24
#define BATCH 2
#define LOG2E 1.44269504088896340736f

typedef unsigned short ushort_t;
typedef unsigned int uint_t;
typedef short bf16x4 __attribute__((ext_vector_type(4)));
typedef short bf16x8 __attribute__((ext_vector_type(8)));
typedef float f32x4 __attribute__((ext_vector_type(4)));

static __device__ inline ushort_t f2bf_rne(float x) {
    uint_t u = __builtin_bit_cast(uint_t, x);
    u = (u + 0x7FFFu + ((u >> 16) & 1u)) >> 16;
    return (ushort_t)u;
}

static __device__ inline float fast_exp2(float x) {
#if __has_builtin(__builtin_amdgcn_exp2f)
    return __builtin_amdgcn_exp2f(x);
#else
    return exp2f(x);
#endif
}

// 16x16 score tile, K-dim = 16 (exact I). Both operands are 4 bf16/lane at
// k-slot quad*4+j. Preferred: native 16x16x16 (half the pipe work, b64 loads).
// Fallback: 16x16x32 with both operands slot-padded (same per-lane slot
// permutation on both sides -> identical dot product).
static __device__ inline f32x4 score_mfma(bf16x4 a, bf16x4 b, f32x4 c) {
#if __has_builtin(__builtin_amdgcn_mfma_f32_16x16x16bf16_1k)
    return __builtin_amdgcn_mfma_f32_16x16x16bf16_1k(a, b, c, 0, 0, 0);
#elif __has_builtin(__builtin_amdgcn_mfma_f32_16x16x16_bf16)
    return __builtin_amdgcn_mfma_f32_16x16x16_bf16(a, b, c, 0, 0, 0);
#else
    int2 ai = __builtin_bit_cast(int2, a);
    int2 bi = __builtin_bit_cast(int2, b);
    int4 a4 = make_int4(ai.x, ai.y, 0, 0);
    int4 b4 = make_int4(bi.x, bi.y, 0, 0);
    return __builtin_amdgcn_mfma_f32_16x16x32_bf16(
        __builtin_bit_cast(bf16x8, a4), __builtin_bit_cast(bf16x8, b4), c, 0, 0, 0);
#endif
}

// ---------------------------------------------------------------------------
// Kernel 1: QKV projection -> bf16 (q pre-scaled by log2e). R7 version
// (TLP-first): 1152 blocks x 256 threads; thread = (voxel n in 16, i in 16).
// ---------------------------------------------------------------------------
__global__ __launch_bounds__(256) void qkv_kernel(
    const float* __restrict__ x,
    const float* __restrict__ Wq, const float* __restrict__ bq,
    const float* __restrict__ Wk, const float* __restrict__ bk,
    const float* __restrict__ Wv, const float* __restrict__ bv,
    ushort_t* __restrict__ qb, ushort_t* __restrict__ kb,
    ushort_t* __restrict__ vT)
{
    __shared__ float ws[3][I_CH][132];   // padded stride 132 -> conflict-free
    __shared__ float xs[C_CH][I_CH];     // 8 KB

    const int t    = threadIdx.x;
    const int vox0 = blockIdx.x * 16;
    const int b    = vox0 / NVOX;
    const int n0   = vox0 - b * NVOX;

    {
        const int i  = t >> 4;           // 0..15
        const int c8 = (t & 15) * 8;     // 0..120
        const float4* wq4 = (const float4*)(Wq + i * C_CH + c8);
        const float4* wk4 = (const float4*)(Wk + i * C_CH + c8);
        const float4* wv4 = (const float4*)(Wv + i * C_CH + c8);
        *(float4*)&ws[0][i][c8]     = wq4[0];
        *(float4*)&ws[0][i][c8 + 4] = wq4[1];
        *(float4*)&ws[1][i][c8]     = wk4[0];
        *(float4*)&ws[1][i][c8 + 4] = wk4[1];
        *(float4*)&ws[2][i][c8]     = wv4[0];
        *(float4*)&ws[2][i][c8 + 4] = wv4[1];
    }

    {
        const float* xb = x + (size_t)b * C_CH * NVOX + n0;
        const int c   = t >> 2;          // 0..63
        const int col = (t & 3) * 4;
        *(float4*)&xs[c][col]      = *(const float4*)(xb + (size_t)c * NVOX + col);
        *(float4*)&xs[c + 64][col] = *(const float4*)(xb + (size_t)(c + 64) * NVOX + col);
    }
    __syncthreads();

    const int n = t & 15;
    const int i = t >> 4;

    float aq = 0.f, ak = 0.f, av = 0.f;
    #pragma unroll 4
    for (int c = 0; c < C_CH; c += 4) {
        float x0 = xs[c + 0][n];
        float x1 = xs[c + 1][n];
        float x2 = xs[c + 2][n];
        float x3 = xs[c + 3][n];
        float4 wq = *(const float4*)&ws[0][i][c];
        float4 wk = *(const float4*)&ws[1][i][c];
        float4 wv = *(const float4*)&ws[2][i][c];
        aq = fmaf(wq.x, x0, fmaf(wq.y, x1, fmaf(wq.z, x2, fmaf(wq.w, x3, aq))));
        ak = fmaf(wk.x, x0, fmaf(wk.y, x1, fmaf(wk.z, x2, fmaf(wk.w, x3, ak))));
        av = fmaf(wv.x, x0, fmaf(wv.y, x1, fmaf(wv.z, x2, fmaf(wv.w, x3, av))));
    }

    const size_t vox = (size_t)vox0 + n;
    qb[vox * I_CH + i] = f2bf_rne((aq + bq[i]) * LOG2E);
    kb[vox * I_CH + i] = f2bf_rne(ak + bk[i]);
    vT[((size_t)b * I_CH + i) * NVOX + n0 + n] = f2bf_rne(av + bv[i]);
}

// ---------------------------------------------------------------------------
// Kernel 2: fused MFMA flash attention + combine + output projection + resid.
// R5 structure (best measured: 46.2 us): 576 blocks x 512 threads (8 waves),
// 32 queries/block; wave w covers keys [w*1152, (w+1)*1152) in 36 steps of
// 32 keys with 1-step register prefetch.
// ROUND 9 delta: score MFMAs use 16x16x16 (K = I = 16 exact) -> K loads are
// b64 (no duplicated halves, 1KB/step unique vs 2KB issued), no zeroed
// quads in Q-frag, half the score matrix-pipe work. Key permutation
// pi(r) = 8*(r>>2) + (r&3) [+4 tile1] keeps the exp->perm->PV handoff
// identical (rows r = quad*4+reg). PV/L MFMAs unchanged (full K=32).
// Epilogue: LDS reduce, /l, Wo projection, residual. LDS <=2-way padded;
// no dynamic register indexing (round-4's scratch-spill bug).
// ---------------------------------------------------------------------------
__global__ __launch_bounds__(512) void attn_kernel(
    const ushort_t* __restrict__ qb, const ushort_t* __restrict__ kb,
    const ushort_t* __restrict__ vT,
    const float* __restrict__ Wo, const float* __restrict__ bo,
    const float* __restrict__ gamma, const float* __restrict__ x,
    float* __restrict__ out)
{
    __shared__ float po[4][32][18];     // partial O; stride 18 -> <=2-way
    __shared__ float lsh[8][33];        // per-wave l (32 q), stride 33
    __shared__ float aot[16][40];       // ao[i][q], stride 40 (16B rows)
    __shared__ float wo_s[C_CH][17];    // Wo, stride 17 -> conflict-free

    const int tid  = threadIdx.x;
    const int w    = tid >> 6;
    const int lane = tid & 63;
    const int l16  = lane & 15;
    const int quad = lane >> 4;

    // stage Wo: thread -> (c = tid>>2, i0 = (tid&3)*4), coalesced float4 read
    {
        const int c  = tid >> 2;
        const int i4 = (tid & 3) * 4;
        float4 wv = *(const float4*)(Wo + c * I_CH + i4);
        wo_s[c][i4 + 0] = wv.x; wo_s[c][i4 + 1] = wv.y;
        wo_s[c][i4 + 2] = wv.z; wo_s[c][i4 + 3] = wv.w;
    }

    const int qvox0 = blockIdx.x * 32;
    const int b     = qvox0 / NVOX;
    const int nloc0 = qvox0 - b * NVOX;

    // Q B-frags for 16x16x16: lane (q=l16, quad) holds i = quad*4..+3 (b64)
    bf16x4 qf0 = __builtin_bit_cast(bf16x4,
        *(const int2*)(qb + (size_t)(qvox0 + l16) * I_CH + quad * 4));
    bf16x4 qf1 = __builtin_bit_cast(bf16x4,
        *(const int2*)(qb + (size_t)(qvox0 + 16 + l16) * I_CH + quad * 4));

    // key permutation: score-row r -> key 8*(r>>2) + (r&3)  [+4 for tile1]
    const int p0     = ((l16 >> 2) << 3) + (l16 & 3);
    const int mchunk = w * (NVOX / 8);          // 1152 keys per wave
    const ushort_t* kp = kb + ((size_t)b * NVOX + mchunk + p0) * I_CH + quad * 4;
    const ushort_t* vp = vT + ((size_t)b * I_CH + l16) * NVOX + mchunk + quad * 8;

    f32x4 O0 = {0.f,0.f,0.f,0.f}, O1 = {0.f,0.f,0.f,0.f};
    f32x4 L0 = {0.f,0.f,0.f,0.f}, L1 = {0.f,0.f,0.f,0.f};
    const f32x4 Z = {0.f,0.f,0.f,0.f};
    int4 onesi; onesi.x = onesi.y = onesi.z = onesi.w = 0x3F803F80;  // bf16 1.0
    const bf16x8 ones = __builtin_bit_cast(bf16x8, onesi);

    int2 ka0 = *(const int2*)(kp);
    int2 ka1 = *(const int2*)(kp + 4 * I_CH);   // +4 keys (tile 1)
    int4 va  = *(const int4*)(vp);

    #pragma unroll 2
    for (int it = 0; it < NVOX / 8 / 32; ++it) {
        kp += 32 * I_CH;
        vp += 32;
        int2 ka0n = *(const int2*)(kp);            // prefetch next step
        int2 ka1n = *(const int2*)(kp + 4 * I_CH);
        int4 van  = *(const int4*)(vp);

        bf16x4 kA0 = __builtin_bit_cast(bf16x4, ka0);
        bf16x4 kA1 = __builtin_bit_cast(bf16x4, ka1);
        f32x4 s00 = score_mfma(kA0, qf0, Z);
        f32x4 s01 = score_mfma(kA1, qf0, Z);
        f32x4 s10 = score_mfma(kA0, qf1, Z);
        f32x4 s11 = score_mfma(kA1, qf1, Z);

        // qtile 0
        {
            float p00 = fast_exp2(s00.x), p01 = fast_exp2(s00.y);
            float p02 = fast_exp2(s00.z), p03 = fast_exp2(s00.w);
            float p10 = fast_exp2(s01.x), p11 = fast_exp2(s01.y);
            float p12 = fast_exp2(s01.z), p13 = fast_exp2(s01.w);
            uint_t d0 = __builtin_amdgcn_perm(__builtin_bit_cast(uint_t, p01),
                                              __builtin_bit_cast(uint_t, p00), 0x07060302u);
            uint_t d1 = __builtin_amdgcn_perm(__builtin_bit_cast(uint_t, p03),
                                              __builtin_bit_cast(uint_t, p02), 0x07060302u);
            uint_t d2 = __builtin_amdgcn_perm(__builtin_bit_cast(uint_t, p11),
                                              __builtin_bit_cast(uint_t, p10), 0x07060302u);
            uint_t d3 = __builtin_amdgcn_perm(__builtin_bit_cast(uint_t, p13),
                                              __builtin_bit_cast(uint_t, p12), 0x07060302u);
            int4 pbi = make_int4((int)d0, (int)d1, (int)d2, (int)d3);
            bf16x8 pb = __builtin_bit_cast(bf16x8, pbi);
            O0 = __builtin_amdgcn_mfma_f32_16x16x32_bf16(
                __builtin_bit_cast(bf16x8, va), pb, O0, 0, 0, 0);
            L0 = __builtin_amdgcn_mfma_f32_16x16x32_bf16(ones, pb, L0, 0, 0, 0);
        }
        // qtile 1
        {
            float p00 = fast_exp2(s10.x), p01 = fast_exp2(s10.y);
            float p02 = fast_exp2(s10.z), p03 = fast_exp2(s10.w);
            float p10 = fast_exp2(s11.x), p11 = fast_exp2(s11.y);
            float p12 = fast_exp2(s11.z), p13 = fast_exp2(s11.w);
            uint_t d0 = __builtin_amdgcn_perm(__builtin_bit_cast(uint_t, p01),
                                              __builtin_bit_cast(uint_t, p00), 0x07060302u);
            uint_t d1 = __builtin_amdgcn_perm(__builtin_bit_cast(uint_t, p03),
                                              __builtin_bit_cast(uint_t, p02), 0x07060302u);
            uint_t d2 = __builtin_amdgcn_perm(__builtin_bit_cast(uint_t, p11),
                                              __builtin_bit_cast(uint_t, p10), 0x07060302u);
            uint_t d3 = __builtin_amdgcn_perm(__builtin_bit_cast(uint_t, p13),
                                              __builtin_bit_cast(uint_t, p12), 0x07060302u);
            int4 pbi = make_int4((int)d0, (int)d1, (int)d2, (int)d3);
            bf16x8 pb = __builtin_bit_cast(bf16x8, pbi);
            O1 = __builtin_amdgcn_mfma_f32_16x16x32_bf16(
                __builtin_bit_cast(bf16x8, va), pb, O1, 0, 0, 0);
            L1 = __builtin_amdgcn_mfma_f32_16x16x32_bf16(ones, pb, L1, 0, 0, 0);
        }

        ka0 = ka0n; ka1 = ka1n; va = van;
    }

    // ---- stage A: waves 0-3 deposit O; every wave deposits l ----
    if (w < 4) {
        #pragma unroll
        for (int r = 0; r < 4; ++r) {
            po[w][quad * 4 + r][l16]      = O0[r];   // qtile0: rows 0..15
            po[w][16 + quad * 4 + r][l16] = O1[r];   // qtile1: rows 16..31
        }
    }
    if (quad == 0) { lsh[w][l16] = L0.x; lsh[w][16 + l16] = L1.x; }
    __syncthreads();

    // ---- stage B: waves 4-7 accumulate into slot w-4 ----
    if (w >= 4) {
        #pragma unroll
        for (int r = 0; r < 4; ++r) {
            po[w - 4][quad * 4 + r][l16]      += O0[r];
            po[w - 4][16 + quad * 4 + r][l16] += O1[r];
        }
    }
    __syncthreads();

    // ---- combine: 512 threads -> aot[i][q] = (sum O)/(sum l) ----
    {
        const int q32 = tid & 31;
        const int i   = tid >> 5;           // 0..15
        const int row = (q32 >> 4) * 16 + i;
        const int col = q32 & 15;
        float v = 0.f, l = 0.f;
        #pragma unroll
        for (int ww = 0; ww < 4; ++ww) v += po[ww][row][col];
        #pragma unroll
        for (int ww = 0; ww < 8; ++ww) l += lsh[ww][q32];
        aot[i][q32] = v / l;
    }
    __syncthreads();

    // ---- projection + residual: thread -> (c = tid>>2, 8 queries) ----
    const float g  = gamma[0];
    const int   c  = tid >> 2;          // 0..127
    const int   qh = (tid & 3) * 8;     // 0,8,16,24

    float acc[8];
    {
        const float b0 = bo[c];
        #pragma unroll
        for (int q = 0; q < 8; ++q) acc[q] = b0;
    }
    #pragma unroll
    for (int i = 0; i < 16; ++i) {
        const float wv = wo_s[c][i];
        float4 a0 = *(const float4*)&aot[i][qh];
        float4 a1 = *(const float4*)&aot[i][qh + 4];
        acc[0] = fmaf(wv, a0.x, acc[0]); acc[1] = fmaf(wv, a0.y, acc[1]);
        acc[2] = fmaf(wv, a0.z, acc[2]); acc[3] = fmaf(wv, a0.w, acc[3]);
        acc[4] = fmaf(wv, a1.x, acc[4]); acc[5] = fmaf(wv, a1.y, acc[5]);
        acc[6] = fmaf(wv, a1.z, acc[6]); acc[7] = fmaf(wv, a1.w, acc[7]);
    }

    const size_t gi = ((size_t)b * C_CH + c) * NVOX + nloc0 + qh;
    float4 x0 = *(const float4*)(x + gi);
    float4 x1 = *(const float4*)(x + gi + 4);
    float4 o0, o1;
    o0.x = fmaf(g, acc[0], x0.x); o0.y = fmaf(g, acc[1], x0.y);
    o0.z = fmaf(g, acc[2], x0.z); o0.w = fmaf(g, acc[3], x0.w);
    o1.x = fmaf(g, acc[4], x1.x); o1.y = fmaf(g, acc[5], x1.y);
    o1.z = fmaf(g, acc[6], x1.z); o1.w = fmaf(g, acc[7], x1.w);
    *(float4*)(out + gi)     = o0;
    *(float4*)(out + gi + 4) = o1;
}

// ---------------------------------------------------------------------------
extern "C" void kernel_launch(void* const* d_in, const int* in_sizes, int n_in,
                              void* d_out, int out_size, void* d_ws, size_t ws_size,
                              hipStream_t stream) {
    const float* x     = (const float*)d_in[0];
    const float* Wq    = (const float*)d_in[1];
    const float* bq    = (const float*)d_in[2];
    const float* Wk    = (const float*)d_in[3];
    const float* bk    = (const float*)d_in[4];
    const float* Wv    = (const float*)d_in[5];
    const float* bv    = (const float*)d_in[6];
    const float* Wo    = (const float*)d_in[7];
    const float* bo    = (const float*)d_in[8];
    const float* gamma = (const float*)d_in[9];
    float* out = (float*)d_out;

    ushort_t* qb = (ushort_t*)d_ws;
    ushort_t* kb = qb + (size_t)BATCH * NVOX * I_CH;
    ushort_t* vT = kb + (size_t)BATCH * NVOX * I_CH;
    // attn prefetch may read ~64B past a wave's K/V range; ws slack covers it.

    hipLaunchKernelGGL(qkv_kernel, dim3(BATCH * NVOX / 16), dim3(256), 0, stream,
                       x, Wq, bq, Wk, bk, Wv, bv, qb, kb, vT);
    hipLaunchKernelGGL(attn_kernel, dim3(BATCH * NVOX / 32), dim3(512), 0, stream,
                       qb, kb, vT, Wo, bo, gamma, x, out);
}

// Round 10
// 114.151 us; speedup vs baseline: 1.4024x; 1.1201x over previous
//
#include <hip/hip_runtime.h>

#define C_CH 128
#define I_CH 16
#define NVOX 9216   // 16*24*24
#define BATCH 2
#define NGRP (NVOX / 32)   // 288 key-groups per batch
#define LOG2E 1.44269504088896340736f

typedef unsigned short ushort_t;
typedef unsigned int uint_t;
typedef short bf16x4 __attribute__((ext_vector_type(4)));
typedef short bf16x8 __attribute__((ext_vector_type(8)));
typedef float f32x4 __attribute__((ext_vector_type(4)));

static __device__ inline ushort_t f2bf_rne(float x) {
    uint_t u = __builtin_bit_cast(uint_t, x);
    u = (u + 0x7FFFu + ((u >> 16) & 1u)) >> 16;
    return (ushort_t)u;
}

static __device__ inline float fast_exp2(float x) {
#if __has_builtin(__builtin_amdgcn_exp2f)
    return __builtin_amdgcn_exp2f(x);
#else
    return exp2f(x);
#endif
}

// 16x16x16 score MFMA (K = I = 16 exact); fallback pads K-slots on both
// operands identically (same dot product).
static __device__ inline f32x4 score_mfma(bf16x4 a, bf16x4 b, f32x4 c) {
#if __has_builtin(__builtin_amdgcn_mfma_f32_16x16x16bf16_1k)
    return __builtin_amdgcn_mfma_f32_16x16x16bf16_1k(a, b, c, 0, 0, 0);
#elif __has_builtin(__builtin_amdgcn_mfma_f32_16x16x16_bf16)
    return __builtin_amdgcn_mfma_f32_16x16x16_bf16(a, b, c, 0, 0, 0);
#else
    int2 ai = __builtin_bit_cast(int2, a);
    int2 bi = __builtin_bit_cast(int2, b);
    int4 a4 = make_int4(ai.x, ai.y, 0, 0);
    int4 b4 = make_int4(bi.x, bi.y, 0, 0);
    return __builtin_amdgcn_mfma_f32_16x16x32_bf16(
        __builtin_bit_cast(bf16x8, a4), __builtin_bit_cast(bf16x8, b4), c, 0, 0, 0);
#endif
}

// ---------------------------------------------------------------------------
// Kernel 1: QKV projection -> bf16.
// ROUND 10: K and V are written in MFMA-FRAGMENT-MAJOR order so the attn
// kernel's inner-loop loads are lane-contiguous (lane L reads base+L*chunk):
//   kfrag[b][g][tile][lane][4]  (ushort; g = 32-key group, tile in {0,1},
//     lane = (i>>2)*16 + l16 where key = pi(l16)+4*tile, pi(r)=8*(r>>2)+(r&3))
//   vfrag[b][g][lane][8]        (lane = (koff>>3)*16 + i, koff = key&31)
// qb stays voxel-major (read once per wave at attn start).
// ---------------------------------------------------------------------------
__global__ __launch_bounds__(256) void qkv_kernel(
    const float* __restrict__ x,
    const float* __restrict__ Wq, const float* __restrict__ bq,
    const float* __restrict__ Wk, const float* __restrict__ bk,
    const float* __restrict__ Wv, const float* __restrict__ bv,
    ushort_t* __restrict__ qb, ushort_t* __restrict__ kfrag,
    ushort_t* __restrict__ vfrag)
{
    __shared__ float ws[3][I_CH][132];   // padded stride 132 -> conflict-free
    __shared__ float xs[C_CH][I_CH];     // 8 KB

    const int t    = threadIdx.x;
    const int vox0 = blockIdx.x * 16;
    const int b    = vox0 / NVOX;
    const int n0   = vox0 - b * NVOX;

    {
        const int i  = t >> 4;           // 0..15
        const int c8 = (t & 15) * 8;     // 0..120
        const float4* wq4 = (const float4*)(Wq + i * C_CH + c8);
        const float4* wk4 = (const float4*)(Wk + i * C_CH + c8);
        const float4* wv4 = (const float4*)(Wv + i * C_CH + c8);
        *(float4*)&ws[0][i][c8]     = wq4[0];
        *(float4*)&ws[0][i][c8 + 4] = wq4[1];
        *(float4*)&ws[1][i][c8]     = wk4[0];
        *(float4*)&ws[1][i][c8 + 4] = wk4[1];
        *(float4*)&ws[2][i][c8]     = wv4[0];
        *(float4*)&ws[2][i][c8 + 4] = wv4[1];
    }

    {
        const float* xb = x + (size_t)b * C_CH * NVOX + n0;
        const int c   = t >> 2;          // 0..63
        const int col = (t & 3) * 4;
        *(float4*)&xs[c][col]      = *(const float4*)(xb + (size_t)c * NVOX + col);
        *(float4*)&xs[c + 64][col] = *(const float4*)(xb + (size_t)(c + 64) * NVOX + col);
    }
    __syncthreads();

    const int n = t & 15;
    const int i = t >> 4;

    float aq = 0.f, ak = 0.f, av = 0.f;
    #pragma unroll 4
    for (int c = 0; c < C_CH; c += 4) {
        float x0 = xs[c + 0][n];
        float x1 = xs[c + 1][n];
        float x2 = xs[c + 2][n];
        float x3 = xs[c + 3][n];
        float4 wq = *(const float4*)&ws[0][i][c];
        float4 wk = *(const float4*)&ws[1][i][c];
        float4 wv = *(const float4*)&ws[2][i][c];
        aq = fmaf(wq.x, x0, fmaf(wq.y, x1, fmaf(wq.z, x2, fmaf(wq.w, x3, aq))));
        ak = fmaf(wk.x, x0, fmaf(wk.y, x1, fmaf(wk.z, x2, fmaf(wk.w, x3, ak))));
        av = fmaf(wv.x, x0, fmaf(wv.y, x1, fmaf(wv.z, x2, fmaf(wv.w, x3, av))));
    }

    const int nl     = n0 + n;           // local voxel (key index) in batch
    const size_t vox = (size_t)b * NVOX + nl;
    qb[vox * I_CH + i] = f2bf_rne((aq + bq[i]) * LOG2E);

    const int g   = nl >> 5;             // 32-key group
    const int k32 = nl & 31;
    const size_t gbase = ((size_t)b * NGRP + g) * 512;

    // K fragment slot: tile = (k32>>2)&1 ; m = k32 - 4*tile (bit2 clear);
    // l16 = 4*(m>>3) + (m&3); lane = (i>>2)*16 + l16; elem = i&3.
    {
        const int tile = (k32 >> 2) & 1;
        const int m    = k32 - 4 * tile;
        const int l16  = ((m >> 3) << 2) | (m & 3);
        const int lane = ((i >> 2) << 4) | l16;
        kfrag[gbase + tile * 256 + lane * 4 + (i & 3)] = f2bf_rne(ak + bk[i]);
    }
    // V fragment slot: lane = (k32>>3)*16 + i; elem = k32&7.
    {
        const int lane = ((k32 >> 3) << 4) | i;
        vfrag[gbase + lane * 8 + (k32 & 7)] = f2bf_rne(av + bv[i]);
    }
}

// ---------------------------------------------------------------------------
// Kernel 2: fused MFMA flash attention + combine + output projection + resid.
// R5/R9 structure: 576 blocks x 512 threads (8 waves), 32 queries/block;
// wave w covers key-groups [w*36, (w+1)*36) (1152 keys) with 1-step
// register prefetch.
// ROUND 10 delta: K/V loads are frag-major -> every inner-loop load is
// lane-contiguous (base + lane*8 or lane*16), one coalesced transaction,
// replacing the 64-scattered-address pattern (theory: TA address-divergence
// serialization was the ~46us invariant). Math identical to R9.
// ---------------------------------------------------------------------------
__global__ __launch_bounds__(512) void attn_kernel(
    const ushort_t* __restrict__ qb, const ushort_t* __restrict__ kfrag,
    const ushort_t* __restrict__ vfrag,
    const float* __restrict__ Wo, const float* __restrict__ bo,
    const float* __restrict__ gamma, const float* __restrict__ x,
    float* __restrict__ out)
{
    __shared__ float po[4][32][18];     // partial O; stride 18 -> <=2-way
    __shared__ float lsh[8][33];        // per-wave l (32 q), stride 33
    __shared__ float aot[16][40];       // ao[i][q], stride 40 (16B rows)
    __shared__ float wo_s[C_CH][17];    // Wo, stride 17 -> conflict-free

    const int tid  = threadIdx.x;
    const int w    = tid >> 6;
    const int lane = tid & 63;
    const int l16  = lane & 15;
    const int quad = lane >> 4;

    // stage Wo: thread -> (c = tid>>2, i0 = (tid&3)*4), coalesced float4 read
    {
        const int c  = tid >> 2;
        const int i4 = (tid & 3) * 4;
        float4 wv = *(const float4*)(Wo + c * I_CH + i4);
        wo_s[c][i4 + 0] = wv.x; wo_s[c][i4 + 1] = wv.y;
        wo_s[c][i4 + 2] = wv.z; wo_s[c][i4 + 3] = wv.w;
    }

    const int qvox0 = blockIdx.x * 32;
    const int b     = qvox0 / NVOX;
    const int nloc0 = qvox0 - b * NVOX;

    // Q B-frags for 16x16x16: lane (q=l16, quad) holds i = quad*4..+3 (b64)
    bf16x4 qf0 = __builtin_bit_cast(bf16x4,
        *(const int2*)(qb + (size_t)(qvox0 + l16) * I_CH + quad * 4));
    bf16x4 qf1 = __builtin_bit_cast(bf16x4,
        *(const int2*)(qb + (size_t)(qvox0 + 16 + l16) * I_CH + quad * 4));

    // frag-major bases: wave w starts at group w*36 of batch b
    const ushort_t* kp = kfrag + ((size_t)b * NGRP + w * 36) * 512 + lane * 4;
    const ushort_t* vp = vfrag + ((size_t)b * NGRP + w * 36) * 512 + lane * 8;

    f32x4 O0 = {0.f,0.f,0.f,0.f}, O1 = {0.f,0.f,0.f,0.f};
    f32x4 L0 = {0.f,0.f,0.f,0.f}, L1 = {0.f,0.f,0.f,0.f};
    const f32x4 Z = {0.f,0.f,0.f,0.f};
    int4 onesi; onesi.x = onesi.y = onesi.z = onesi.w = 0x3F803F80;  // bf16 1.0
    const bf16x8 ones = __builtin_bit_cast(bf16x8, onesi);

    int2 ka0 = *(const int2*)(kp);
    int2 ka1 = *(const int2*)(kp + 256);
    int4 va  = *(const int4*)(vp);

    #pragma unroll 2
    for (int it = 0; it < 36; ++it) {
        kp += 512;
        vp += 512;
        int2 ka0n = *(const int2*)(kp);            // prefetch next group
        int2 ka1n = *(const int2*)(kp + 256);
        int4 van  = *(const int4*)(vp);

        bf16x4 kA0 = __builtin_bit_cast(bf16x4, ka0);
        bf16x4 kA1 = __builtin_bit_cast(bf16x4, ka1);
        f32x4 s00 = score_mfma(kA0, qf0, Z);
        f32x4 s01 = score_mfma(kA1, qf0, Z);
        f32x4 s10 = score_mfma(kA0, qf1, Z);
        f32x4 s11 = score_mfma(kA1, qf1, Z);

        // qtile 0
        {
            float p00 = fast_exp2(s00.x), p01 = fast_exp2(s00.y);
            float p02 = fast_exp2(s00.z), p03 = fast_exp2(s00.w);
            float p10 = fast_exp2(s01.x), p11 = fast_exp2(s01.y);
            float p12 = fast_exp2(s01.z), p13 = fast_exp2(s01.w);
            uint_t d0 = __builtin_amdgcn_perm(__builtin_bit_cast(uint_t, p01),
                                              __builtin_bit_cast(uint_t, p00), 0x07060302u);
            uint_t d1 = __builtin_amdgcn_perm(__builtin_bit_cast(uint_t, p03),
                                              __builtin_bit_cast(uint_t, p02), 0x07060302u);
            uint_t d2 = __builtin_amdgcn_perm(__builtin_bit_cast(uint_t, p11),
                                              __builtin_bit_cast(uint_t, p10), 0x07060302u);
            uint_t d3 = __builtin_amdgcn_perm(__builtin_bit_cast(uint_t, p13),
                                              __builtin_bit_cast(uint_t, p12), 0x07060302u);
            int4 pbi = make_int4((int)d0, (int)d1, (int)d2, (int)d3);
            bf16x8 pb = __builtin_bit_cast(bf16x8, pbi);
            O0 = __builtin_amdgcn_mfma_f32_16x16x32_bf16(
                __builtin_bit_cast(bf16x8, va), pb, O0, 0, 0, 0);
            L0 = __builtin_amdgcn_mfma_f32_16x16x32_bf16(ones, pb, L0, 0, 0, 0);
        }
        // qtile 1
        {
            float p00 = fast_exp2(s10.x), p01 = fast_exp2(s10.y);
            float p02 = fast_exp2(s10.z), p03 = fast_exp2(s10.w);
            float p10 = fast_exp2(s11.x), p11 = fast_exp2(s11.y);
            float p12 = fast_exp2(s11.z), p13 = fast_exp2(s11.w);
            uint_t d0 = __builtin_amdgcn_perm(__builtin_bit_cast(uint_t, p01),
                                              __builtin_bit_cast(uint_t, p00), 0x07060302u);
            uint_t d1 = __builtin_amdgcn_perm(__builtin_bit_cast(uint_t, p03),
                                              __builtin_bit_cast(uint_t, p02), 0x07060302u);
            uint_t d2 = __builtin_amdgcn_perm(__builtin_bit_cast(uint_t, p11),
                                              __builtin_bit_cast(uint_t, p10), 0x07060302u);
            uint_t d3 = __builtin_amdgcn_perm(__builtin_bit_cast(uint_t, p13),
                                              __builtin_bit_cast(uint_t, p12), 0x07060302u);
            int4 pbi = make_int4((int)d0, (int)d1, (int)d2, (int)d3);
            bf16x8 pb = __builtin_bit_cast(bf16x8, pbi);
            O1 = __builtin_amdgcn_mfma_f32_16x16x32_bf16(
                __builtin_bit_cast(bf16x8, va), pb, O1, 0, 0, 0);
            L1 = __builtin_amdgcn_mfma_f32_16x16x32_bf16(ones, pb, L1, 0, 0, 0);
        }

        ka0 = ka0n; ka1 = ka1n; va = van;
    }

    // ---- stage A: waves 0-3 deposit O; every wave deposits l ----
    if (w < 4) {
        #pragma unroll
        for (int r = 0; r < 4; ++r) {
            po[w][quad * 4 + r][l16]      = O0[r];   // qtile0: rows 0..15
            po[w][16 + quad * 4 + r][l16] = O1[r];   // qtile1: rows 16..31
        }
    }
    if (quad == 0) { lsh[w][l16] = L0.x; lsh[w][16 + l16] = L1.x; }
    __syncthreads();

    // ---- stage B: waves 4-7 accumulate into slot w-4 ----
    if (w >= 4) {
        #pragma unroll
        for (int r = 0; r < 4; ++r) {
            po[w - 4][quad * 4 + r][l16]      += O0[r];
            po[w - 4][16 + quad * 4 + r][l16] += O1[r];
        }
    }
    __syncthreads();

    // ---- combine: 512 threads -> aot[i][q] = (sum O)/(sum l) ----
    {
        const int q32 = tid & 31;
        const int i   = tid >> 5;           // 0..15
        const int row = (q32 >> 4) * 16 + i;
        const int col = q32 & 15;
        float v = 0.f, l = 0.f;
        #pragma unroll
        for (int ww = 0; ww < 4; ++ww) v += po[ww][row][col];
        #pragma unroll
        for (int ww = 0; ww < 8; ++ww) l += lsh[ww][q32];
        aot[i][q32] = v / l;
    }
    __syncthreads();

    // ---- projection + residual: thread -> (c = tid>>2, 8 queries) ----
    const float g  = gamma[0];
    const int   c  = tid >> 2;          // 0..127
    const int   qh = (tid & 3) * 8;     // 0,8,16,24

    float acc[8];
    {
        const float b0 = bo[c];
        #pragma unroll
        for (int q = 0; q < 8; ++q) acc[q] = b0;
    }
    #pragma unroll
    for (int i = 0; i < 16; ++i) {
        const float wv = wo_s[c][i];
        float4 a0 = *(const float4*)&aot[i][qh];
        float4 a1 = *(const float4*)&aot[i][qh + 4];
        acc[0] = fmaf(wv, a0.x, acc[0]); acc[1] = fmaf(wv, a0.y, acc[1]);
        acc[2] = fmaf(wv, a0.z, acc[2]); acc[3] = fmaf(wv, a0.w, acc[3]);
        acc[4] = fmaf(wv, a1.x, acc[4]); acc[5] = fmaf(wv, a1.y, acc[5]);
        acc[6] = fmaf(wv, a1.z, acc[6]); acc[7] = fmaf(wv, a1.w, acc[7]);
    }

    const size_t gi = ((size_t)b * C_CH + c) * NVOX + nloc0 + qh;
    float4 x0 = *(const float4*)(x + gi);
    float4 x1 = *(const float4*)(x + gi + 4);
    float4 o0, o1;
    o0.x = fmaf(g, acc[0], x0.x); o0.y = fmaf(g, acc[1], x0.y);
    o0.z = fmaf(g, acc[2], x0.z); o0.w = fmaf(g, acc[3], x0.w);
    o1.x = fmaf(g, acc[4], x1.x); o1.y = fmaf(g, acc[5], x1.y);
    o1.z = fmaf(g, acc[6], x1.z); o1.w = fmaf(g, acc[7], x1.w);
    *(float4*)(out + gi)     = o0;
    *(float4*)(out + gi + 4) = o1;
}

// ---------------------------------------------------------------------------
extern "C" void kernel_launch(void* const* d_in, const int* in_sizes, int n_in,
                              void* d_out, int out_size, void* d_ws, size_t ws_size,
                              hipStream_t stream) {
    const float* x     = (const float*)d_in[0];
    const float* Wq    = (const float*)d_in[1];
    const float* bq    = (const float*)d_in[2];
    const float* Wk    = (const float*)d_in[3];
    const float* bk    = (const float*)d_in[4];
    const float* Wv    = (const float*)d_in[5];
    const float* bv    = (const float*)d_in[6];
    const float* Wo    = (const float*)d_in[7];
    const float* bo    = (const float*)d_in[8];
    const float* gamma = (const float*)d_in[9];
    float* out = (float*)d_out;

    ushort_t* qb    = (ushort_t*)d_ws;
    ushort_t* kfrag = qb    + (size_t)BATCH * NVOX * I_CH;   // 294912 ushorts
    ushort_t* vfrag = kfrag + (size_t)BATCH * NGRP * 512;    // 294912 ushorts
    // attn prefetch may read one group (1KB) past a wave's range; ws slack
    // and adjacent arrays cover it (values never used).

    hipLaunchKernelGGL(qkv_kernel, dim3(BATCH * NVOX / 16), dim3(256), 0, stream,
                       x, Wq, bq, Wk, bk, Wv, bv, qb, kfrag, vfrag);
    hipLaunchKernelGGL(attn_kernel, dim3(BATCH * NVOX / 32), dim3(512), 0, stream,
                       qb, kfrag, vfrag, Wo, bo, gamma, x, out);
}